// Round 13
// baseline (220.743 us; speedup 1.0000x reference)
//
#include <hip/hip_runtime.h>
#include <hip/hip_bf16.h>

#define NN 100000
#define NE 3200000
#define FIN 128
#define HD 16
#define CD 2

#define BSH 9                        // bucket shift
#define BSPAN 512                    // nodes per bucket
#define NBKT 196                     // ceil(NN / BSPAN)
#define CHUNK 8192                   // edges per partition block
#define NPB ((NE + CHUNK - 1) / CHUNK)   // 391

__device__ __forceinline__ float bf2f(ushort u) {
    union { float f; unsigned int i; } v; v.i = ((unsigned int)u) << 16; return v.f;
}
__device__ __forceinline__ ushort f2b(float f) {
    union { float f; unsigned int u; } v; v.f = f;
    unsigned int r = (v.u + 0x7FFFu + ((v.u >> 16) & 1u)) >> 16;   // RNE
    return (ushort)r;
}

// ---- head: gemm1 (unscaled, 1 task/thread) + bucket histogram (blocks < NPB) ----
__global__ __launch_bounds__(512) void k_head(const int* __restrict__ dst,
                                              const float* __restrict__ x,
                                              const float* __restrict__ W1,
                                              int* __restrict__ cntmat,
                                              ushort* __restrict__ h1b) {
    __shared__ float wsm[FIN][HD];   // 8 KB
    __shared__ int h[NBKT];
    int b = blockIdx.x, t = threadIdx.x;
    for (int i = t; i < FIN * HD; i += 512) wsm[i >> 4][i & 15] = W1[i];
    for (int i = t; i < NBKT; i += 512) h[i] = 0;
    __syncthreads();
    // histogram part (only first NPB blocks)
    if (b < NPB) {
        int cq = b * (CHUNK / 4);
        const int4* d4 = (const int4*)dst;
        #pragma unroll
        for (int j = 0; j < CHUNK / 2048; ++j) {
            int e4 = cq + j * 512 + t;
            if (e4 < NE / 4) {
                int4 d = d4[e4];
                atomicAdd(&h[d.x >> BSH], 1);
                atomicAdd(&h[d.y >> BSH], 1);
                atomicAdd(&h[d.z >> BSH], 1);
                atomicAdd(&h[d.w >> BSH], 1);
            }
        }
    }
    // gemm part: one task per thread (NN*4 tasks over 782 blocks x 512)
    int task = b * 512 + t;
    if (task < NN * 4) {
        int node = task >> 2;
        int g = (task & 3) * 4;
        const float4* xr = (const float4*)(x + (size_t)node * FIN);
        float a0 = 0.f, a1 = 0.f, a2 = 0.f, a3 = 0.f;
        #pragma unroll
        for (int k4 = 0; k4 < FIN / 4; ++k4) {
            float4 v = xr[k4];
            #pragma unroll
            for (int kk = 0; kk < 4; ++kk) {
                float vk = (kk == 0) ? v.x : (kk == 1) ? v.y : (kk == 2) ? v.z : v.w;
                float4 w = *(const float4*)&wsm[k4 * 4 + kk][g];
                a0 += vk * w.x;
                a1 += vk * w.y;
                a2 += vk * w.z;
                a3 += vk * w.w;
            }
        }
        ushort4 r = {f2b(a0), f2b(a1), f2b(a2), f2b(a3)};   // UNSCALED
        *(ushort4*)(h1b + (size_t)node * HD + g) = r;
    }
    if (b < NPB) {
        __syncthreads();
        int* row = cntmat + (size_t)b * NBKT;
        for (int i = t; i < NBKT; i += 512) row[i] = h[i];
    }
}

// ---- column-wise exclusive scan -> relm[bucket][b], btot ----
__global__ __launch_bounds__(512) void k_colscan(const int* __restrict__ cntmat,
                                                 int* __restrict__ relm,
                                                 int* __restrict__ btot) {
    __shared__ int sm[512];
    int j = blockIdx.x, t = threadIdx.x;
    int v = (t < NPB) ? cntmat[(size_t)t * NBKT + j] : 0;
    sm[t] = v;
    __syncthreads();
    for (int off = 1; off < 512; off <<= 1) {
        int u = 0;
        if (t >= off) u = sm[t - off];
        __syncthreads();
        if (t >= off) sm[t] += u;
        __syncthreads();
    }
    if (t < NPB) relm[(size_t)j * NPB + t] = t ? sm[t - 1] : 0;
    if (t == 511) btot[j] = sm[511];
}

// ---- partition: inline btot-scan preamble, then single edge pass ----
__global__ __launch_bounds__(512) void k_part(const int* __restrict__ src,
                                              const int* __restrict__ dst,
                                              const int* __restrict__ btot,
                                              const int* __restrict__ relm,
                                              unsigned int* __restrict__ csrb) {
    __shared__ int sb[256];
    __shared__ int cur[NBKT];
    int b = blockIdx.x, t = threadIdx.x;
    if (t < 256) sb[t] = (t < NBKT) ? btot[t] : 0;
    __syncthreads();
    for (int off = 1; off < 256; off <<= 1) {
        int u = 0;
        if (t < 256 && t >= off) u = sb[t - off];
        __syncthreads();
        if (t < 256 && t >= off) sb[t] += u;
        __syncthreads();
    }
    // boff[i] = (i ? sb[i-1] : 0)
    for (int i = t; i < NBKT; i += 512)
        cur[i] = (i ? sb[i - 1] : 0) + relm[(size_t)i * NPB + b];
    __syncthreads();
    int cq = b * (CHUNK / 4);
    const int4* s4 = (const int4*)src;
    const int4* d4 = (const int4*)dst;
    #pragma unroll
    for (int j = 0; j < CHUNK / 2048; ++j) {
        int e4 = cq + j * 512 + t;
        if (e4 < NE / 4) {
            int4 s = s4[e4];
            int4 d = d4[e4];
            int p;
            p = atomicAdd(&cur[d.x >> BSH], 1);
            csrb[p] = (unsigned)s.x | ((unsigned)(d.x & (BSPAN - 1)) << 17);
            p = atomicAdd(&cur[d.y >> BSH], 1);
            csrb[p] = (unsigned)s.y | ((unsigned)(d.y & (BSPAN - 1)) << 17);
            p = atomicAdd(&cur[d.z >> BSH], 1);
            csrb[p] = (unsigned)s.z | ((unsigned)(d.z & (BSPAN - 1)) << 17);
            p = atomicAdd(&cur[d.w >> BSH], 1);
            csrb[p] = (unsigned)s.w | ((unsigned)(d.w & (BSPAN - 1)) << 17);
        }
    }
}

// ---- per-bucket counting sort -> csr2/rowptr/dinv, then scale h1b by dinv ----
__global__ __launch_bounds__(512) void k_sorts(const int* __restrict__ btot,
                                               const unsigned int* __restrict__ csrb,
                                               int* __restrict__ csr2,
                                               int* __restrict__ rowptr,
                                               float* __restrict__ dinv,
                                               ushort* __restrict__ h1b) {
    __shared__ int sb[256];
    __shared__ int cnt[BSPAN];
    __shared__ int sc[BSPAN];
    __shared__ int cur[BSPAN];
    __shared__ float sdv[BSPAN];
    int b = blockIdx.x, t = threadIdx.x;
    if (t < 256) sb[t] = (t < NBKT) ? btot[t] : 0;
    cnt[t] = 0;
    __syncthreads();
    for (int off = 1; off < 256; off <<= 1) {
        int u = 0;
        if (t < 256 && t >= off) u = sb[t - off];
        __syncthreads();
        if (t < 256 && t >= off) sb[t] += u;
        __syncthreads();
    }
    int e0 = b ? sb[b - 1] : 0;
    int e1 = sb[b];
    __syncthreads();
    for (int e = e0 + t; e < e1; e += 512) atomicAdd(&cnt[csrb[e] >> 17], 1);
    __syncthreads();
    sc[t] = cnt[t];
    __syncthreads();
    for (int off = 1; off < BSPAN; off <<= 1) {
        int v = 0;
        if (t >= off) v = sc[t - off];
        __syncthreads();
        if (t >= off) sc[t] += v;
        __syncthreads();
    }
    {
        int ex = e0 + (t ? sc[t - 1] : 0);
        cur[t] = ex;
        float di = rsqrtf((float)cnt[t] + 1.0f);
        sdv[t] = di;
        int node = b * BSPAN + t;
        if (node < NN) {
            rowptr[node] = ex;
            dinv[node] = di;
        }
    }
    if (b == 0 && t == 0) rowptr[NN] = NE;
    __syncthreads();
    for (int e = e0 + t; e < e1; e += 512) {
        unsigned p = csrb[e];
        int pos = atomicAdd(&cur[p >> 17], 1);
        csr2[pos] = (int)(p & 0x1FFFF);
    }
    // scale this bucket's h1b rows by dinv (one node per thread, 4x ushort4)
    {
        int node = b * BSPAN + t;
        if (node < NN) {
            float di = sdv[t];
            ushort4* hp = (ushort4*)(h1b + (size_t)node * HD);
            #pragma unroll
            for (int j = 0; j < 4; ++j) {
                ushort4 u = hp[j];
                u.x = f2b(bf2f(u.x) * di);
                u.y = f2b(bf2f(u.y) * di);
                u.z = f2b(bf2f(u.z) * di);
                u.w = f2b(bf2f(u.w) * di);
                hp[j] = u;
            }
        }
    }
}

// ---- layer-1 aggregate + ReLU + fused (h2 @ W2)*dinv : 4 nodes per wave ----
__global__ __launch_bounds__(256) void k_agg1(const int* __restrict__ rowptr,
                                              const int* __restrict__ csr2,
                                              const ushort* __restrict__ h1b,
                                              const float* __restrict__ dinv,
                                              const float* __restrict__ b1,
                                              const float* __restrict__ W2,
                                              float* __restrict__ g_s) {
    int wid = (blockIdx.x * 256 + threadIdx.x) >> 6;
    int lane = threadIdx.x & 63;
    int node = wid * 4 + (lane >> 4);
    if (node >= NN) return;
    int l16 = lane & 15;
    int slot = l16 >> 2;              // 0..3
    int fq = (lane & 3) * 4;          // 0,4,8,12
    int e0 = rowptr[node], e1 = rowptr[node + 1];
    float a0 = 0.f, a1 = 0.f, a2 = 0.f, a3 = 0.f;
    float c0 = 0.f, c1 = 0.f, c2 = 0.f, c3 = 0.f;
    int e = e0 + slot;
    for (; e + 4 < e1; e += 8) {                 // 2 independent chains
        int s0 = csr2[e];
        int s1 = csr2[e + 4];
        ushort4 u0 = *(const ushort4*)(h1b + (size_t)s0 * HD + fq);
        ushort4 u1 = *(const ushort4*)(h1b + (size_t)s1 * HD + fq);
        a0 += bf2f(u0.x); a1 += bf2f(u0.y); a2 += bf2f(u0.z); a3 += bf2f(u0.w);
        c0 += bf2f(u1.x); c1 += bf2f(u1.y); c2 += bf2f(u1.z); c3 += bf2f(u1.w);
    }
    if (e < e1) {
        ushort4 u = *(const ushort4*)(h1b + (size_t)csr2[e] * HD + fq);
        a0 += bf2f(u.x); a1 += bf2f(u.y); a2 += bf2f(u.z); a3 += bf2f(u.w);
    }
    a0 += c0; a1 += c1; a2 += c2; a3 += c3;
    #pragma unroll
    for (int m = 4; m <= 8; m <<= 1) {
        a0 += __shfl_xor(a0, m, 64);
        a1 += __shfl_xor(a1, m, 64);
        a2 += __shfl_xor(a2, m, 64);
        a3 += __shfl_xor(a3, m, 64);
    }
    if (slot == 0) {                  // lanes l16=0..3 hold features fq..fq+3
        float di = dinv[node];
        ushort4 us = *(const ushort4*)(h1b + (size_t)node * HD + fq);
        float v0 = fmaxf(di * (a0 + bf2f(us.x)) + b1[fq],     0.f);
        float v1 = fmaxf(di * (a1 + bf2f(us.y)) + b1[fq + 1], 0.f);
        float v2 = fmaxf(di * (a2 + bf2f(us.z)) + b1[fq + 2], 0.f);
        float v3 = fmaxf(di * (a3 + bf2f(us.w)) + b1[fq + 3], 0.f);
        float p0 = v0 * W2[fq * 2]       + v1 * W2[(fq + 1) * 2]
                 + v2 * W2[(fq + 2) * 2] + v3 * W2[(fq + 3) * 2];
        float p1 = v0 * W2[fq * 2 + 1]       + v1 * W2[(fq + 1) * 2 + 1]
                 + v2 * W2[(fq + 2) * 2 + 1] + v3 * W2[(fq + 3) * 2 + 1];
        p0 += __shfl_xor(p0, 1, 64); p0 += __shfl_xor(p0, 2, 64);
        p1 += __shfl_xor(p1, 1, 64); p1 += __shfl_xor(p1, 2, 64);
        if (l16 == 0) {
            float2 r = {p0 * di, p1 * di};
            *(float2*)(g_s + (size_t)node * 2) = r;
        }
    }
}

// ---- layer-2 aggregate: 4 nodes per wave, 8 slots x 2 feats, fused softmax ----
__global__ __launch_bounds__(256) void k_agg2(const int* __restrict__ rowptr,
                                              const int* __restrict__ csr2,
                                              const float* __restrict__ g_s,
                                              const float* __restrict__ dinv,
                                              const float* __restrict__ b2,
                                              float* __restrict__ out) {
    int wid = (blockIdx.x * 256 + threadIdx.x) >> 6;
    int lane = threadIdx.x & 63;
    int node = wid * 4 + (lane >> 4);
    if (node >= NN) return;
    int l16 = lane & 15;
    int slot = l16 >> 1, f = lane & 1;
    int e0 = rowptr[node], e1 = rowptr[node + 1];
    float acc = 0.f;
    for (int e = e0 + slot; e < e1; e += 8)
        acc += g_s[(size_t)csr2[e] * 2 + f];
    #pragma unroll
    for (int m = 2; m <= 8; m <<= 1) acc += __shfl_xor(acc, m, 64);
    if (slot == 0) {                  // lanes l16=0,1
        float di = dinv[node];
        float o = di * (acc + g_s[(size_t)node * 2 + f]) + b2[f];
        float other = __shfl_xor(o, 1, 64);
        float mx = fmaxf(o, other);
        float l = mx + logf(__expf(o - mx) + __expf(other - mx));
        out[(size_t)node * 2 + f] = o - l;
    }
}

extern "C" void kernel_launch(void* const* d_in, const int* in_sizes, int n_in,
                              void* d_out, int out_size, void* d_ws, size_t ws_size,
                              hipStream_t stream) {
    const float* x   = (const float*)d_in[0];
    const int* ei    = (const int*)d_in[1];
    const int* src   = ei;
    const int* dst   = ei + NE;
    const float* W1  = (const float*)d_in[2];
    const float* b1  = (const float*)d_in[3];
    const float* W2  = (const float*)d_in[4];
    const float* b2  = (const float*)d_in[5];
    float* out = (float*)d_out;

    char* w = (char*)d_ws;
    float* dinv        = (float*)w;          w += NN * 4;
    int*   btot        = (int*)w;            w += NBKT * 4;
    int*   rowptr      = (int*)w;            w += (NN + 1) * 4;
    int*   cntmat      = (int*)w;            w += (size_t)NPB * NBKT * 4;   // 306 KB
    int*   relm        = (int*)w;            w += (size_t)NBKT * NPB * 4;   // 306 KB
    unsigned int* csrb = (unsigned int*)w;   w += (size_t)NE * 4;           // 12.8 MB
    int*   csr2        = (int*)w;            w += (size_t)NE * 4;           // 12.8 MB
    ushort* h1b        = (ushort*)w;         w += (size_t)NN * HD * 2;      // 3.2 MB
    float* g_s         = (float*)w;          w += NN * CD * 4;

    k_head   <<<(NN * 4 + 511) / 512, 512, 0, stream>>>(dst, x, W1, cntmat, h1b);
    k_colscan<<<NBKT, 512, 0, stream>>>(cntmat, relm, btot);
    k_part   <<<NPB, 512, 0, stream>>>(src, dst, btot, relm, csrb);
    k_sorts  <<<NBKT, 512, 0, stream>>>(btot, csrb, csr2, rowptr, dinv, h1b);
    k_agg1   <<<(NN * 16 + 255) / 256, 256, 0, stream>>>(rowptr, csr2, h1b, dinv, b1, W2, g_s);
    k_agg2   <<<(NN * 16 + 255) / 256, 256, 0, stream>>>(rowptr, csr2, g_s, dinv, b2, out);
}

// Round 14
// 211.942 us; speedup vs baseline: 1.0415x; 1.0415x over previous
//
#include <hip/hip_runtime.h>
#include <hip/hip_bf16.h>

#define NN 100000
#define NE 3200000
#define FIN 128
#define HD 16
#define CD 2

#define BSH 8                        // bucket shift
#define BSPAN 256                    // nodes per bucket
#define NBKT 391                     // ceil(NN / BSPAN)
#define CHUNK 8192                   // edges per partition block
#define NPB ((NE + CHUNK - 1) / CHUNK)   // 391

__device__ __forceinline__ float bf2f(ushort u) {
    union { float f; unsigned int i; } v; v.i = ((unsigned int)u) << 16; return v.f;
}
__device__ __forceinline__ ushort f2b(float f) {
    union { float f; unsigned int u; } v; v.f = f;
    unsigned int r = (v.u + 0x7FFFu + ((v.u >> 16) & 1u)) >> 16;   // RNE
    return (ushort)r;
}

// ---- pass 1: per-block bucket counts -> cntmat[b][bucket] ----
__global__ __launch_bounds__(512) void k_cnt(const int* __restrict__ dst,
                                             int* __restrict__ cntmat) {
    __shared__ int h[NBKT];
    for (int i = threadIdx.x; i < NBKT; i += 512) h[i] = 0;
    __syncthreads();
    int cq = blockIdx.x * (CHUNK / 4);
    const int4* d4 = (const int4*)dst;
    #pragma unroll
    for (int j = 0; j < CHUNK / 2048; ++j) {
        int e4 = cq + j * 512 + threadIdx.x;
        if (e4 < NE / 4) {
            int4 d = d4[e4];
            atomicAdd(&h[d.x >> BSH], 1);
            atomicAdd(&h[d.y >> BSH], 1);
            atomicAdd(&h[d.z >> BSH], 1);
            atomicAdd(&h[d.w >> BSH], 1);
        }
    }
    __syncthreads();
    int* row = cntmat + (size_t)blockIdx.x * NBKT;
    for (int i = threadIdx.x; i < NBKT; i += 512) row[i] = h[i];
}

// ---- pass 2: column-wise exclusive scan -> relm[bucket][b], btot ----
__global__ __launch_bounds__(512) void k_colscan(const int* __restrict__ cntmat,
                                                 int* __restrict__ relm,
                                                 int* __restrict__ btot) {
    __shared__ int sm[512];
    int j = blockIdx.x, t = threadIdx.x;
    int v = (t < NPB) ? cntmat[(size_t)t * NBKT + j] : 0;
    sm[t] = v;
    __syncthreads();
    for (int off = 1; off < 512; off <<= 1) {
        int u = 0;
        if (t >= off) u = sm[t - off];
        __syncthreads();
        if (t >= off) sm[t] += u;
        __syncthreads();
    }
    if (t < NPB) relm[(size_t)j * NPB + t] = t ? sm[t - 1] : 0;
    if (t == 511) btot[j] = sm[511];
}

// ---- pass 3: partition (inline boff scan preamble), single edge pass ----
__global__ __launch_bounds__(512) void k_part(const int* __restrict__ src,
                                              const int* __restrict__ dst,
                                              const int* __restrict__ btot,
                                              const int* __restrict__ relm,
                                              unsigned int* __restrict__ csrb) {
    __shared__ int sb[512];
    __shared__ int cur[NBKT];
    int b = blockIdx.x, t = threadIdx.x;
    sb[t] = (t < NBKT) ? btot[t] : 0;
    __syncthreads();
    for (int off = 1; off < 512; off <<= 1) {
        int u = 0;
        if (t >= off) u = sb[t - off];
        __syncthreads();
        if (t >= off) sb[t] += u;
        __syncthreads();
    }
    for (int i = t; i < NBKT; i += 512)
        cur[i] = (i ? sb[i - 1] : 0) + relm[(size_t)i * NPB + b];
    __syncthreads();
    int cq = b * (CHUNK / 4);
    const int4* s4 = (const int4*)src;
    const int4* d4 = (const int4*)dst;
    #pragma unroll
    for (int j = 0; j < CHUNK / 2048; ++j) {
        int e4 = cq + j * 512 + t;
        if (e4 < NE / 4) {
            int4 s = s4[e4];
            int4 d = d4[e4];
            int p;
            p = atomicAdd(&cur[d.x >> BSH], 1);
            csrb[p] = (unsigned)s.x | ((unsigned)(d.x & (BSPAN - 1)) << 17);
            p = atomicAdd(&cur[d.y >> BSH], 1);
            csrb[p] = (unsigned)s.y | ((unsigned)(d.y & (BSPAN - 1)) << 17);
            p = atomicAdd(&cur[d.z >> BSH], 1);
            csrb[p] = (unsigned)s.z | ((unsigned)(d.z & (BSPAN - 1)) << 17);
            p = atomicAdd(&cur[d.w >> BSH], 1);
            csrb[p] = (unsigned)s.w | ((unsigned)(d.w & (BSPAN - 1)) << 17);
        }
    }
}

// ---- pass 4: per-bucket counting sort (inline boff scan) -> csr2, rowptr, dinv ----
__global__ __launch_bounds__(512) void k_sortb(const int* __restrict__ btot,
                                               const unsigned int* __restrict__ csrb,
                                               int* __restrict__ csr2,
                                               int* __restrict__ rowptr,
                                               float* __restrict__ dinv) {
    __shared__ int sb[512];
    __shared__ int cnt[BSPAN];
    __shared__ int sc[BSPAN];
    __shared__ int cur[BSPAN];
    int b = blockIdx.x, t = threadIdx.x;
    sb[t] = (t < NBKT) ? btot[t] : 0;
    if (t < BSPAN) cnt[t] = 0;
    __syncthreads();
    for (int off = 1; off < 512; off <<= 1) {
        int u = 0;
        if (t >= off) u = sb[t - off];
        __syncthreads();
        if (t >= off) sb[t] += u;
        __syncthreads();
    }
    int e0 = b ? sb[b - 1] : 0;
    int e1 = sb[b];
    __syncthreads();
    for (int e = e0 + t; e < e1; e += 512) atomicAdd(&cnt[csrb[e] >> 17], 1);
    __syncthreads();
    if (t < BSPAN) sc[t] = cnt[t];
    __syncthreads();
    for (int off = 1; off < BSPAN; off <<= 1) {
        int v = 0;
        if (t < BSPAN && t >= off) v = sc[t - off];
        __syncthreads();
        if (t < BSPAN && t >= off) sc[t] += v;
        __syncthreads();
    }
    if (t < BSPAN) {
        int ex = e0 + (t ? sc[t - 1] : 0);
        cur[t] = ex;
        int node = b * BSPAN + t;
        if (node < NN) {
            rowptr[node] = ex;
            dinv[node] = rsqrtf((float)cnt[t] + 1.0f);
        }
    }
    if (b == 0 && t == 0) rowptr[NN] = NE;
    __syncthreads();
    for (int e = e0 + t; e < e1; e += 512) {
        unsigned p = csrb[e];
        int pos = atomicAdd(&cur[p >> 17], 1);
        csr2[pos] = (int)(p & 0x1FFFF);
    }
}

// ---- h1b = bf16((x @ W1) * dinv[node]) : 4 threads/node, 4 outputs each ----
__global__ __launch_bounds__(256) void k_gemm1(const float* __restrict__ x,
                                               const float* __restrict__ W1,
                                               const float* __restrict__ dinv,
                                               ushort* __restrict__ h1b) {
    __shared__ float wsm[FIN][HD];   // 8 KB
    for (int i = threadIdx.x; i < FIN * HD; i += 256) wsm[i >> 4][i & 15] = W1[i];
    __syncthreads();
    int t = blockIdx.x * 256 + threadIdx.x;
    int node = t >> 2;
    if (node >= NN) return;
    int g = (t & 3) * 4;
    const float4* xr = (const float4*)(x + (size_t)node * FIN);
    float a0 = 0.f, a1 = 0.f, a2 = 0.f, a3 = 0.f;
    #pragma unroll
    for (int k4 = 0; k4 < FIN / 4; ++k4) {
        float4 v = xr[k4];
        #pragma unroll
        for (int kk = 0; kk < 4; ++kk) {
            float vk = (kk == 0) ? v.x : (kk == 1) ? v.y : (kk == 2) ? v.z : v.w;
            float4 w = *(const float4*)&wsm[k4 * 4 + kk][g];
            a0 += vk * w.x;
            a1 += vk * w.y;
            a2 += vk * w.z;
            a3 += vk * w.w;
        }
    }
    float di = dinv[node];
    ushort4 r = {f2b(a0 * di), f2b(a1 * di), f2b(a2 * di), f2b(a3 * di)};
    *(ushort4*)(h1b + (size_t)node * HD + g) = r;
}

// ---- layer-1 aggregate + ReLU + fused (h2 @ W2)*dinv : 4 nodes per wave ----
__global__ __launch_bounds__(256) void k_agg1(const int* __restrict__ rowptr,
                                              const int* __restrict__ csr2,
                                              const ushort* __restrict__ h1b,
                                              const float* __restrict__ dinv,
                                              const float* __restrict__ b1,
                                              const float* __restrict__ W2,
                                              float* __restrict__ g_s) {
    int wid = (blockIdx.x * 256 + threadIdx.x) >> 6;
    int lane = threadIdx.x & 63;
    int node = wid * 4 + (lane >> 4);
    if (node >= NN) return;
    int l16 = lane & 15;
    int slot = l16 >> 2;              // 0..3
    int fq = (lane & 3) * 4;          // 0,4,8,12
    int e0 = rowptr[node], e1 = rowptr[node + 1];
    float a0 = 0.f, a1 = 0.f, a2 = 0.f, a3 = 0.f;
    float c0 = 0.f, c1 = 0.f, c2 = 0.f, c3 = 0.f;
    int e = e0 + slot;
    for (; e + 4 < e1; e += 8) {                 // 2 independent chains
        int s0 = csr2[e];
        int s1 = csr2[e + 4];
        ushort4 u0 = *(const ushort4*)(h1b + (size_t)s0 * HD + fq);
        ushort4 u1 = *(const ushort4*)(h1b + (size_t)s1 * HD + fq);
        a0 += bf2f(u0.x); a1 += bf2f(u0.y); a2 += bf2f(u0.z); a3 += bf2f(u0.w);
        c0 += bf2f(u1.x); c1 += bf2f(u1.y); c2 += bf2f(u1.z); c3 += bf2f(u1.w);
    }
    if (e < e1) {
        ushort4 u = *(const ushort4*)(h1b + (size_t)csr2[e] * HD + fq);
        a0 += bf2f(u.x); a1 += bf2f(u.y); a2 += bf2f(u.z); a3 += bf2f(u.w);
    }
    a0 += c0; a1 += c1; a2 += c2; a3 += c3;
    #pragma unroll
    for (int m = 4; m <= 8; m <<= 1) {
        a0 += __shfl_xor(a0, m, 64);
        a1 += __shfl_xor(a1, m, 64);
        a2 += __shfl_xor(a2, m, 64);
        a3 += __shfl_xor(a3, m, 64);
    }
    if (slot == 0) {                  // lanes l16=0..3 hold features fq..fq+3
        float di = dinv[node];
        ushort4 us = *(const ushort4*)(h1b + (size_t)node * HD + fq);
        float v0 = fmaxf(di * (a0 + bf2f(us.x)) + b1[fq],     0.f);
        float v1 = fmaxf(di * (a1 + bf2f(us.y)) + b1[fq + 1], 0.f);
        float v2 = fmaxf(di * (a2 + bf2f(us.z)) + b1[fq + 2], 0.f);
        float v3 = fmaxf(di * (a3 + bf2f(us.w)) + b1[fq + 3], 0.f);
        float p0 = v0 * W2[fq * 2]       + v1 * W2[(fq + 1) * 2]
                 + v2 * W2[(fq + 2) * 2] + v3 * W2[(fq + 3) * 2];
        float p1 = v0 * W2[fq * 2 + 1]       + v1 * W2[(fq + 1) * 2 + 1]
                 + v2 * W2[(fq + 2) * 2 + 1] + v3 * W2[(fq + 3) * 2 + 1];
        p0 += __shfl_xor(p0, 1, 64); p0 += __shfl_xor(p0, 2, 64);
        p1 += __shfl_xor(p1, 1, 64); p1 += __shfl_xor(p1, 2, 64);
        if (l16 == 0) {
            float2 r = {p0 * di, p1 * di};
            *(float2*)(g_s + (size_t)node * 2) = r;
        }
    }
}

// ---- layer-2 aggregate: 4 nodes per wave, 8 slots x 2 feats, fused softmax ----
__global__ __launch_bounds__(256) void k_agg2(const int* __restrict__ rowptr,
                                              const int* __restrict__ csr2,
                                              const float* __restrict__ g_s,
                                              const float* __restrict__ dinv,
                                              const float* __restrict__ b2,
                                              float* __restrict__ out) {
    int wid = (blockIdx.x * 256 + threadIdx.x) >> 6;
    int lane = threadIdx.x & 63;
    int node = wid * 4 + (lane >> 4);
    if (node >= NN) return;
    int l16 = lane & 15;
    int slot = l16 >> 1, f = lane & 1;
    int e0 = rowptr[node], e1 = rowptr[node + 1];
    float acc = 0.f;
    for (int e = e0 + slot; e < e1; e += 8)
        acc += g_s[(size_t)csr2[e] * 2 + f];
    #pragma unroll
    for (int m = 2; m <= 8; m <<= 1) acc += __shfl_xor(acc, m, 64);
    if (slot == 0) {                  // lanes l16=0,1
        float di = dinv[node];
        float o = di * (acc + g_s[(size_t)node * 2 + f]) + b2[f];
        float other = __shfl_xor(o, 1, 64);
        float mx = fmaxf(o, other);
        float l = mx + logf(__expf(o - mx) + __expf(other - mx));
        out[(size_t)node * 2 + f] = o - l;
    }
}

extern "C" void kernel_launch(void* const* d_in, const int* in_sizes, int n_in,
                              void* d_out, int out_size, void* d_ws, size_t ws_size,
                              hipStream_t stream) {
    const float* x   = (const float*)d_in[0];
    const int* ei    = (const int*)d_in[1];
    const int* src   = ei;
    const int* dst   = ei + NE;
    const float* W1  = (const float*)d_in[2];
    const float* b1  = (const float*)d_in[3];
    const float* W2  = (const float*)d_in[4];
    const float* b2  = (const float*)d_in[5];
    float* out = (float*)d_out;

    char* w = (char*)d_ws;
    float* dinv        = (float*)w;          w += NN * 4;
    int*   btot        = (int*)w;            w += NBKT * 4;
    int*   rowptr      = (int*)w;            w += (NN + 1) * 4;
    int*   cntmat      = (int*)w;            w += (size_t)NPB * NBKT * 4;   // 611 KB
    int*   relm        = (int*)w;            w += (size_t)NBKT * NPB * 4;   // 611 KB
    unsigned int* csrb = (unsigned int*)w;   w += (size_t)NE * 4;           // 12.8 MB
    int*   csr2        = (int*)w;            w += (size_t)NE * 4;           // 12.8 MB
    ushort* h1b        = (ushort*)w;         w += (size_t)NN * HD * 2;      // 3.2 MB
    float* g_s         = (float*)w;          w += NN * CD * 4;

    k_cnt    <<<NPB, 512, 0, stream>>>(dst, cntmat);
    k_colscan<<<NBKT, 512, 0, stream>>>(cntmat, relm, btot);
    k_part   <<<NPB, 512, 0, stream>>>(src, dst, btot, relm, csrb);
    k_sortb  <<<NBKT, 512, 0, stream>>>(btot, csrb, csr2, rowptr, dinv);
    k_gemm1  <<<(NN * 4 + 255) / 256, 256, 0, stream>>>(x, W1, dinv, h1b);
    k_agg1   <<<(NN * 16 + 255) / 256, 256, 0, stream>>>(rowptr, csr2, h1b, dinv, b1, W2, g_s);
    k_agg2   <<<(NN * 16 + 255) / 256, 256, 0, stream>>>(rowptr, csr2, g_s, dinv, b2, out);
}